// Round 1
// baseline (255.182 us; speedup 1.0000x reference)
//
#include <hip/hip_runtime.h>
#include <math.h>

typedef __attribute__((ext_vector_type(8))) __bf16 bf16x8;
typedef __attribute__((ext_vector_type(4))) __bf16 bf16x4v;
typedef __attribute__((ext_vector_type(4))) float f32x4;

#define N_TOK  4096
#define C_DIM  1024
#define N_EXP  8
#define CAP    4096

// workspace layout (bytes)
#define WS_CNT   0
#define WS_PERM  4096
#define WS_WTS   (WS_PERM + CAP*N_EXP*4)            // 135168
#define WS_XB    ((size_t)1 << 20)                  // 1 MiB: x in bf16 (8 MiB)
#define WS_WT    (WS_XB + (size_t)N_TOK*C_DIM*2)    // 9437184: W^T in bf16 (16 MiB)

// ---------------------------------------------------------------------------
// Router: one wave per token. Computes logits = x@wg + b (fp32), top-2 with
// jax tie-breaking (strict > keeps lowest index), softmax over the two,
// writes probs, appends (token, weight) to per-expert lists, and emits x in
// bf16 for the MFMA GEMM.
// ---------------------------------------------------------------------------
__global__ __launch_bounds__(256)
void router_kernel(const float* __restrict__ x, const float* __restrict__ wg,
                   const float* __restrict__ bias, __bf16* __restrict__ xb,
                   int* __restrict__ cnt, int* __restrict__ perm,
                   float* __restrict__ wts, float* __restrict__ probs) {
  const int lane = threadIdx.x & 63;
  const int wv   = threadIdx.x >> 6;
  const int t    = blockIdx.x * 4 + wv;

  const float4* xrow = (const float4*)(x + (size_t)t * C_DIM);
  float acc[N_EXP];
#pragma unroll
  for (int e = 0; e < N_EXP; ++e) acc[e] = 0.f;

#pragma unroll
  for (int j = 0; j < 4; ++j) {
    const int idx = j * 64 + lane;       // float4 index within row
    const float4 v = xrow[idx];
    const int i = idx * 4;               // element index
    bf16x4v bv = { (__bf16)v.x, (__bf16)v.y, (__bf16)v.z, (__bf16)v.w };
    *(bf16x4v*)(xb + (size_t)t * C_DIM + i) = bv;
    const float* w0 = wg + (size_t)i * N_EXP;
#pragma unroll
    for (int e = 0; e < N_EXP; ++e)
      acc[e] += v.x * w0[e] + v.y * w0[N_EXP + e] +
                v.z * w0[2 * N_EXP + e] + v.w * w0[3 * N_EXP + e];
  }

#pragma unroll
  for (int off = 32; off >= 1; off >>= 1) {
#pragma unroll
    for (int e = 0; e < N_EXP; ++e) acc[e] += __shfl_xor(acc[e], off, 64);
  }

  if (lane == 0) {
    float l[N_EXP];
#pragma unroll
    for (int e = 0; e < N_EXP; ++e) l[e] = acc[e] + bias[e];
    int e0 = 0;
#pragma unroll
    for (int e = 1; e < N_EXP; ++e) if (l[e] > l[e0]) e0 = e;
    int e1 = (e0 == 0) ? 1 : 0;
#pragma unroll
    for (int e = 0; e < N_EXP; ++e) if (e != e0 && l[e] > l[e1]) e1 = e;
    const float p0 = 1.f / (1.f + expf(l[e1] - l[e0]));
    const float p1 = 1.f - p0;
    probs[t * 2]     = p0;
    probs[t * 2 + 1] = p1;
    int s0 = atomicAdd(&cnt[e0], 1);
    perm[e0 * CAP + s0] = t;  wts[e0 * CAP + s0] = p0;
    int s1 = atomicAdd(&cnt[e1], 1);
    perm[e1 * CAP + s1] = t;  wts[e1 * CAP + s1] = p1;
  }
}

// ---------------------------------------------------------------------------
// Transpose + fp32->bf16 convert: Wt[e][o][i] = (bf16) W[e][i][o]
// 32x32 tiles via LDS (padded +1 to break bank conflicts), 32x8 threads.
// ---------------------------------------------------------------------------
__global__ __launch_bounds__(256)
void transpose_w(const float* __restrict__ W, __bf16* __restrict__ Wt) {
  __shared__ __bf16 tile[32][33];
  const int e  = blockIdx.z;
  const int i0 = blockIdx.y * 32;   // input-row block (i dim)
  const int o0 = blockIdx.x * 32;   // input-col block (o dim)
  const float* We  = W  + (size_t)e * C_DIM * C_DIM;
  __bf16*      Wte = Wt + (size_t)e * C_DIM * C_DIM;
  const int tx = threadIdx.x, ty = threadIdx.y;
#pragma unroll
  for (int j = 0; j < 32; j += 8)
    tile[ty + j][tx] = (__bf16)We[(size_t)(i0 + ty + j) * C_DIM + o0 + tx];
  __syncthreads();
#pragma unroll
  for (int j = 0; j < 32; j += 8)
    Wte[(size_t)(o0 + ty + j) * C_DIM + i0 + tx] = tile[tx][ty + j];
}

// ---------------------------------------------------------------------------
// Grouped GEMM: per expert e, rows = gathered tokens (perm), B = Wt[e].
// 128x128 tile, BK=32 (one MFMA K-step), 4 waves each computing 64x64 via a
// 4x4 grid of mfma_f32_16x16x32_bf16. Epilogue scales by gate weight and
// atomicAdds into y (exactly 2 contributions per element -> deterministic).
// ---------------------------------------------------------------------------
__global__ __launch_bounds__(256)
void moe_gemm(const __bf16* __restrict__ xb, const __bf16* __restrict__ Wt,
              const int* __restrict__ cnt, const int* __restrict__ perm,
              const float* __restrict__ wts, float* __restrict__ y) {
  const int e  = blockIdx.z;
  const int n0 = blockIdx.x * 128;
  const int m0 = blockIdx.y * 128;
  const int count = cnt[e];
  if (m0 >= count) return;

  const int*   permE = perm + e * CAP;
  const float* wtsE  = wts  + e * CAP;
  const __bf16* We   = Wt + (size_t)e * C_DIM * C_DIM;

  __shared__ uint4 AsRaw[512];   // 128 rows x 32 bf16
  __shared__ uint4 BsRaw[512];   // 128 n-rows x 32 bf16 (k-contiguous)
  __bf16* As = (__bf16*)AsRaw;
  __bf16* Bs = (__bf16*)BsRaw;

  const int tid  = threadIdx.x;
  const int lane = tid & 63;
  const int wv   = tid >> 6;
  const int wr = wv >> 1, wc = wv & 1;
  const int mw = wr * 64, nw = wc * 64;
  const int l16 = lane & 15, quad = lane >> 4;

  // staging assignment: thread stages 16B chunk (row=tid>>2, part=tid&3) and
  // the same for row+64, for both A and B.
  const int rp   = tid >> 2;
  const int part = tid & 3;
  const int iA0 = m0 + rp, iA1 = m0 + rp + 64;
  const int tk0 = (iA0 < count) ? permE[iA0] : 0;
  const int tk1 = (iA1 < count) ? permE[iA1] : 0;
  const uint4* gA0 = (const uint4*)xb + (size_t)tk0 * 128 + part;
  const uint4* gA1 = (const uint4*)xb + (size_t)tk1 * 128 + part;
  const uint4* gB0 = (const uint4*)We + (size_t)(n0 + rp) * 128 + part;
  const uint4* gB1 = (const uint4*)We + (size_t)(n0 + rp + 64) * 128 + part;

  f32x4 acc[4][4];
  const f32x4 zero = {0.f, 0.f, 0.f, 0.f};
#pragma unroll
  for (int mi = 0; mi < 4; ++mi)
#pragma unroll
    for (int ni = 0; ni < 4; ++ni) acc[mi][ni] = zero;

  for (int kt = 0; kt < 32; ++kt) {
    const uint4 a0 = gA0[kt * 4];
    const uint4 a1 = gA1[kt * 4];
    const uint4 b0 = gB0[kt * 4];
    const uint4 b1 = gB1[kt * 4];
    AsRaw[tid] = a0; AsRaw[tid + 256] = a1;
    BsRaw[tid] = b0; BsRaw[tid + 256] = b1;
    __syncthreads();

    bf16x8 af[4], bfr[4];
#pragma unroll
    for (int mi = 0; mi < 4; ++mi)
      af[mi] = *(const bf16x8*)(As + (mw + mi * 16 + l16) * 32 + quad * 8);
#pragma unroll
    for (int ni = 0; ni < 4; ++ni)
      bfr[ni] = *(const bf16x8*)(Bs + (nw + ni * 16 + l16) * 32 + quad * 8);
#pragma unroll
    for (int mi = 0; mi < 4; ++mi)
#pragma unroll
      for (int ni = 0; ni < 4; ++ni)
        acc[mi][ni] = __builtin_amdgcn_mfma_f32_16x16x32_bf16(
            af[mi], bfr[ni], acc[mi][ni], 0, 0, 0);
    __syncthreads();
  }

  // epilogue: C/D layout col = lane&15, row = quad*4 + reg
#pragma unroll
  for (int mi = 0; mi < 4; ++mi) {
#pragma unroll
    for (int r = 0; r < 4; ++r) {
      const int i = m0 + mw + mi * 16 + quad * 4 + r;
      if (i < count) {
        const int   t = permE[i];
        const float w = wtsE[i];
        float* yrow = y + (size_t)t * C_DIM + n0 + nw + l16;
#pragma unroll
        for (int ni = 0; ni < 4; ++ni)
          atomicAdd(yrow + ni * 16, w * acc[mi][ni][r]);
      }
    }
  }
}

extern "C" void kernel_launch(void* const* d_in, const int* in_sizes, int n_in,
                              void* d_out, int out_size, void* d_ws, size_t ws_size,
                              hipStream_t stream) {
  const float* x    = (const float*)d_in[0];
  const float* wg   = (const float*)d_in[1];
  const float* bias = (const float*)d_in[2];
  const float* wcfc = (const float*)d_in[3];

  float* y     = (float*)d_out;
  float* probs = y + (size_t)N_TOK * C_DIM;

  char* ws   = (char*)d_ws;
  int*    cnt  = (int*)(ws + WS_CNT);
  int*    perm = (int*)(ws + WS_PERM);
  float*  wts  = (float*)(ws + WS_WTS);
  __bf16* xb   = (__bf16*)(ws + WS_XB);
  __bf16* Wt   = (__bf16*)(ws + WS_WT);

  // zero y (atomic accumulate target) and expert counts
  hipMemsetAsync(d_out, 0, (size_t)out_size * sizeof(float), stream);
  hipMemsetAsync(cnt, 0, N_EXP * sizeof(int), stream);

  router_kernel<<<N_TOK / 4, 256, 0, stream>>>(x, wg, bias, xb, cnt, perm, wts, probs);
  transpose_w<<<dim3(32, 32, 8), dim3(32, 8), 0, stream>>>(wcfc, Wt);
  moe_gemm<<<dim3(8, 32, 8), 256, 0, stream>>>(xb, Wt, cnt, perm, wts, y);
}

// Round 2
// 243.847 us; speedup vs baseline: 1.0465x; 1.0465x over previous
//
#include <hip/hip_runtime.h>
#include <math.h>

typedef __attribute__((ext_vector_type(8))) __bf16 bf16x8;
typedef __attribute__((ext_vector_type(4))) __bf16 bf16x4v;
typedef __attribute__((ext_vector_type(4))) float f32x4;

#define N_TOK  4096
#define C_DIM  1024
#define N_EXP  8
#define CAP    4096

// workspace layout (bytes)
#define WS_CNT   0
#define WS_PERM  4096
#define WS_WTS   (WS_PERM + CAP*N_EXP*4)            // 135168
#define WS_XB    ((size_t)1 << 20)                  // 1 MiB: x in bf16 (8 MiB)
#define WS_WT    (WS_XB + (size_t)N_TOK*C_DIM*2)    // 9437184: W^T in bf16 (16 MiB)

// async global->LDS, 16B per lane. LDS dest is wave-uniform base + lane*16.
#define GLD16(g, l)                                                        \
  __builtin_amdgcn_global_load_lds(                                        \
      (const __attribute__((address_space(1))) void*)(g),                  \
      (__attribute__((address_space(3))) void*)(l), 16, 0, 0)

// ---------------------------------------------------------------------------
// Router: one wave per token. wg (32 KB) is staged TRANSPOSED into LDS once
// per block so the dot-product loop reads it lane-coalesced (the round-1
// version read wg with 512 B lane stride -> 64 cache lines per instruction ->
// 108 us of L1 serialization).
// ---------------------------------------------------------------------------
__global__ __launch_bounds__(256)
void router_kernel(const float* __restrict__ x, const float* __restrict__ wg,
                   const float* __restrict__ bias, __bf16* __restrict__ xb,
                   int* __restrict__ cnt, int* __restrict__ perm,
                   float* __restrict__ wts, float* __restrict__ probs) {
  __shared__ float wgT[N_EXP][C_DIM];   // 32 KB
  const int tid = threadIdx.x;

  // stage + transpose wg: coalesced float4 reads, 2-way-conflict LDS writes (free)
#pragma unroll
  for (int i = 0; i < 8; ++i) {
    const float4 v = ((const float4*)wg)[i * 256 + tid];
    const int f = (i * 256 + tid) * 4;   // element index in wg
    const int c = f >> 3;                // input-channel row
    const int e = f & 7;                 // expert col (0 or 4)
    wgT[e][c] = v.x; wgT[e + 1][c] = v.y; wgT[e + 2][c] = v.z; wgT[e + 3][c] = v.w;
  }
  __syncthreads();

  const int lane = tid & 63;
  const int wv   = tid >> 6;
  const int t    = blockIdx.x * 4 + wv;

  const float4* xrow = (const float4*)(x + (size_t)t * C_DIM);
  float acc[N_EXP];
#pragma unroll
  for (int e = 0; e < N_EXP; ++e) acc[e] = 0.f;

#pragma unroll
  for (int j = 0; j < 4; ++j) {
    const int c4 = j * 64 + lane;        // float4 index within row
    const float4 v = xrow[c4];
    bf16x4v bv = { (__bf16)v.x, (__bf16)v.y, (__bf16)v.z, (__bf16)v.w };
    *(bf16x4v*)(xb + (size_t)t * C_DIM + c4 * 4) = bv;
#pragma unroll
    for (int e = 0; e < N_EXP; ++e) {
      const float4 w = *(const float4*)&wgT[e][c4 * 4];
      acc[e] += v.x * w.x + v.y * w.y + v.z * w.z + v.w * w.w;
    }
  }

#pragma unroll
  for (int off = 32; off >= 1; off >>= 1) {
#pragma unroll
    for (int e = 0; e < N_EXP; ++e) acc[e] += __shfl_xor(acc[e], off, 64);
  }

  if (lane == 0) {
    float l[N_EXP];
#pragma unroll
    for (int e = 0; e < N_EXP; ++e) l[e] = acc[e] + bias[e];
    int e0 = 0;
#pragma unroll
    for (int e = 1; e < N_EXP; ++e) if (l[e] > l[e0]) e0 = e;
    int e1 = (e0 == 0) ? 1 : 0;
#pragma unroll
    for (int e = 0; e < N_EXP; ++e) if (e != e0 && l[e] > l[e1]) e1 = e;
    const float p0 = 1.f / (1.f + expf(l[e1] - l[e0]));
    const float p1 = 1.f - p0;
    probs[t * 2]     = p0;
    probs[t * 2 + 1] = p1;
    int s0 = atomicAdd(&cnt[e0], 1);
    perm[e0 * CAP + s0] = t;  wts[e0 * CAP + s0] = p0;
    int s1 = atomicAdd(&cnt[e1], 1);
    perm[e1 * CAP + s1] = t;  wts[e1 * CAP + s1] = p1;
  }
}

// ---------------------------------------------------------------------------
// Transpose + fp32->bf16 convert: Wt[e][o][i] = (bf16) W[e][i][o]
// ---------------------------------------------------------------------------
__global__ __launch_bounds__(256)
void transpose_w(const float* __restrict__ W, __bf16* __restrict__ Wt) {
  __shared__ __bf16 tile[32][33];
  const int e  = blockIdx.z;
  const int i0 = blockIdx.y * 32;
  const int o0 = blockIdx.x * 32;
  const float* We  = W  + (size_t)e * C_DIM * C_DIM;
  __bf16*      Wte = Wt + (size_t)e * C_DIM * C_DIM;
  const int tx = threadIdx.x, ty = threadIdx.y;
#pragma unroll
  for (int j = 0; j < 32; j += 8)
    tile[ty + j][tx] = (__bf16)We[(size_t)(i0 + ty + j) * C_DIM + o0 + tx];
  __syncthreads();
#pragma unroll
  for (int j = 0; j < 32; j += 8)
    Wte[(size_t)(o0 + ty + j) * C_DIM + i0 + tx] = tile[tx][ty + j];
}

// ---------------------------------------------------------------------------
// Grouped GEMM: 128x128 tile, BK=32, 4 waves x (4x4 of 16x16x32 MFMA).
// Staging via global_load_lds (16B/lane, no VGPR round trip): wave wv fills
// LDS rows [wv*16, wv*16+16) and [64+wv*16, ...) of both A and B tiles; LDS
// is row-major 64 B rows, exactly lane-order-contiguous as required.
// ---------------------------------------------------------------------------
__global__ __launch_bounds__(256)
void moe_gemm(const __bf16* __restrict__ xb, const __bf16* __restrict__ Wt,
              const int* __restrict__ cnt, const int* __restrict__ perm,
              const float* __restrict__ wts, float* __restrict__ y) {
  const int e  = blockIdx.z;
  const int n0 = blockIdx.x * 128;
  const int m0 = blockIdx.y * 128;
  const int count = cnt[e];
  if (m0 >= count) return;

  const int*   permE = perm + e * CAP;
  const float* wtsE  = wts  + e * CAP;
  const __bf16* We   = Wt + (size_t)e * C_DIM * C_DIM;

  __shared__ char AsB[8192];   // 128 rows x 64 B (32 bf16)
  __shared__ char BsB[8192];
  __bf16* As = (__bf16*)AsB;
  __bf16* Bs = (__bf16*)BsB;

  const int tid  = threadIdx.x;
  const int lane = tid & 63;
  const int wv   = tid >> 6;
  const int wr = wv >> 1, wc = wv & 1;
  const int mw = wr * 64, nw = wc * 64;
  const int l16 = lane & 15, quad = lane >> 4;

  // staging: row within tile handled by this lane (chunk0), chunk1 = +64 rows
  const int ra   = wv * 16 + (lane >> 2);
  const int part = lane & 3;
  const int iA0 = m0 + ra, iA1 = m0 + ra + 64;
  const int tk0 = (iA0 < count) ? permE[iA0] : 0;
  const int tk1 = (iA1 < count) ? permE[iA1] : 0;
  const char* gA0 = (const char*)xb + (size_t)tk0 * 2048 + part * 16;
  const char* gA1 = (const char*)xb + (size_t)tk1 * 2048 + part * 16;
  const char* gB0 = (const char*)We + (size_t)(n0 + ra) * 2048 + part * 16;
  const char* gB1 = (const char*)We + (size_t)(n0 + ra + 64) * 2048 + part * 16;
  // wave-uniform LDS bases (lane*16 appended by HW)
  char* ldsA0 = AsB + wv * 1024;
  char* ldsA1 = AsB + 4096 + wv * 1024;
  char* ldsB0 = BsB + wv * 1024;
  char* ldsB1 = BsB + 4096 + wv * 1024;

  f32x4 acc[4][4];
  const f32x4 zero = {0.f, 0.f, 0.f, 0.f};
#pragma unroll
  for (int mi = 0; mi < 4; ++mi)
#pragma unroll
    for (int ni = 0; ni < 4; ++ni) acc[mi][ni] = zero;

  for (int kt = 0; kt < 32; ++kt) {
    const int kb = kt * 64;   // byte offset along K
    GLD16(gA0 + kb, ldsA0);
    GLD16(gA1 + kb, ldsA1);
    GLD16(gB0 + kb, ldsB0);
    GLD16(gB1 + kb, ldsB1);
    __syncthreads();

    bf16x8 af[4], bfr[4];
#pragma unroll
    for (int mi = 0; mi < 4; ++mi)
      af[mi] = *(const bf16x8*)(As + (mw + mi * 16 + l16) * 32 + quad * 8);
#pragma unroll
    for (int ni = 0; ni < 4; ++ni)
      bfr[ni] = *(const bf16x8*)(Bs + (nw + ni * 16 + l16) * 32 + quad * 8);
#pragma unroll
    for (int mi = 0; mi < 4; ++mi)
#pragma unroll
      for (int ni = 0; ni < 4; ++ni)
        acc[mi][ni] = __builtin_amdgcn_mfma_f32_16x16x32_bf16(
            af[mi], bfr[ni], acc[mi][ni], 0, 0, 0);
    __syncthreads();
  }

  // epilogue: C/D layout col = lane&15, row = quad*4 + reg
#pragma unroll
  for (int mi = 0; mi < 4; ++mi) {
#pragma unroll
    for (int r = 0; r < 4; ++r) {
      const int i = m0 + mw + mi * 16 + quad * 4 + r;
      if (i < count) {
        const int   t = permE[i];
        const float w = wtsE[i];
        float* yrow = y + (size_t)t * C_DIM + n0 + nw + l16;
#pragma unroll
        for (int ni = 0; ni < 4; ++ni)
          atomicAdd(yrow + ni * 16, w * acc[mi][ni][r]);
      }
    }
  }
}

extern "C" void kernel_launch(void* const* d_in, const int* in_sizes, int n_in,
                              void* d_out, int out_size, void* d_ws, size_t ws_size,
                              hipStream_t stream) {
  const float* x    = (const float*)d_in[0];
  const float* wg   = (const float*)d_in[1];
  const float* bias = (const float*)d_in[2];
  const float* wcfc = (const float*)d_in[3];

  float* y     = (float*)d_out;
  float* probs = y + (size_t)N_TOK * C_DIM;

  char* ws   = (char*)d_ws;
  int*    cnt  = (int*)(ws + WS_CNT);
  int*    perm = (int*)(ws + WS_PERM);
  float*  wts  = (float*)(ws + WS_WTS);
  __bf16* xb   = (__bf16*)(ws + WS_XB);
  __bf16* Wt   = (__bf16*)(ws + WS_WT);

  hipMemsetAsync(d_out, 0, (size_t)out_size * sizeof(float), stream);
  hipMemsetAsync(cnt, 0, N_EXP * sizeof(int), stream);

  router_kernel<<<N_TOK / 4, 256, 0, stream>>>(x, wg, bias, xb, cnt, perm, wts, probs);
  transpose_w<<<dim3(32, 32, 8), dim3(32, 8), 0, stream>>>(wcfc, Wt);
  moe_gemm<<<dim3(8, 32, 8), 256, 0, stream>>>(xb, Wt, cnt, perm, wts, y);
}

// Round 4
// 141.684 us; speedup vs baseline: 1.8011x; 1.7211x over previous
//
#include <hip/hip_runtime.h>
#include <math.h>

typedef __attribute__((ext_vector_type(8))) __bf16 bf16x8;
typedef __attribute__((ext_vector_type(4))) __bf16 bf16x4v;
typedef __attribute__((ext_vector_type(4))) float f32x4;

#define N_TOK  4096
#define C_DIM  1024
#define N_EXP  8
#define CAP    4096

// workspace layout (bytes) — total 25 MiB, the round-2-proven footprint.
// Slot buffers live in d_out's y region instead (see combine()).
#define WS_CNT    0                                   // 32 B
#define WS_ROUTE  4096                                // 16 KB: e0|e1<<16 per token
#define WS_PERM   32768                               // 128 KB: per-expert slot lists
#define WS_XB     ((size_t)1 << 20)                   // 8 MB: x in bf16
#define WS_WT     (WS_XB + ((size_t)8 << 20))         // 16 MB: W^T bf16 -> ends 25 MiB

// async global->LDS, 16B per lane. LDS dest is wave-uniform base + lane*16.
#define GLD16(g, l)                                                        \
  __builtin_amdgcn_global_load_lds(                                        \
      (const __attribute__((address_space(1))) void*)(g),                  \
      (__attribute__((address_space(3))) void*)(l), 16, 0, 0)

// ---------------------------------------------------------------------------
// Router: one wave per token, no atomics. Writes probs + packed expert pair,
// and emits x as bf16.
// ---------------------------------------------------------------------------
__global__ __launch_bounds__(256)
void router_kernel(const float* __restrict__ x, const float* __restrict__ wg,
                   const float* __restrict__ bias, __bf16* __restrict__ xb,
                   int* __restrict__ routeE, float* __restrict__ probs) {
  __shared__ float wgT[N_EXP][C_DIM];   // 32 KB
  const int tid = threadIdx.x;

#pragma unroll
  for (int i = 0; i < 8; ++i) {
    const float4 v = ((const float4*)wg)[i * 256 + tid];
    const int f = (i * 256 + tid) * 4;
    const int c = f >> 3;
    const int e = f & 7;
    wgT[e][c] = v.x; wgT[e + 1][c] = v.y; wgT[e + 2][c] = v.z; wgT[e + 3][c] = v.w;
  }
  __syncthreads();

  const int lane = tid & 63;
  const int wv   = tid >> 6;
  const int t    = blockIdx.x * 4 + wv;

  const float4* xrow = (const float4*)(x + (size_t)t * C_DIM);
  float acc[N_EXP];
#pragma unroll
  for (int e = 0; e < N_EXP; ++e) acc[e] = 0.f;

#pragma unroll
  for (int j = 0; j < 4; ++j) {
    const int c4 = j * 64 + lane;
    const float4 v = xrow[c4];
    bf16x4v bv = { (__bf16)v.x, (__bf16)v.y, (__bf16)v.z, (__bf16)v.w };
    *(bf16x4v*)(xb + (size_t)t * C_DIM + c4 * 4) = bv;
#pragma unroll
    for (int e = 0; e < N_EXP; ++e) {
      const float4 w = *(const float4*)&wgT[e][c4 * 4];
      acc[e] += v.x * w.x + v.y * w.y + v.z * w.z + v.w * w.w;
    }
  }

#pragma unroll
  for (int off = 32; off >= 1; off >>= 1) {
#pragma unroll
    for (int e = 0; e < N_EXP; ++e) acc[e] += __shfl_xor(acc[e], off, 64);
  }

  if (lane == 0) {
    float l[N_EXP];
#pragma unroll
    for (int e = 0; e < N_EXP; ++e) l[e] = acc[e] + bias[e];
    int e0 = 0;
#pragma unroll
    for (int e = 1; e < N_EXP; ++e) if (l[e] > l[e0]) e0 = e;
    int e1 = (e0 == 0) ? 1 : 0;
#pragma unroll
    for (int e = 0; e < N_EXP; ++e) if (e != e0 && l[e] > l[e1]) e1 = e;
    const float p0 = 1.f / (1.f + expf(l[e1] - l[e0]));
    probs[t * 2]     = p0;
    probs[t * 2 + 1] = 1.f - p0;
    routeE[t] = e0 | (e1 << 16);
  }
}

// ---------------------------------------------------------------------------
// Slot assignment: 64 blocks x 64 tokens; LDS-aggregated, 8 global atomics
// per block. perm entry = token*2 + choice.
// ---------------------------------------------------------------------------
__global__ __launch_bounds__(64)
void build_perm(const int* __restrict__ routeE, int* __restrict__ cnt,
                int* __restrict__ perm) {
  __shared__ int lcnt[N_EXP], base[N_EXP];
  const int tid = threadIdx.x;
  if (tid < N_EXP) lcnt[tid] = 0;
  __syncthreads();
  const int t  = blockIdx.x * 64 + tid;
  const int re = routeE[t];
  const int e0 = re & 0xffff, e1 = re >> 16;
  const int s0 = atomicAdd(&lcnt[e0], 1);
  const int s1 = atomicAdd(&lcnt[e1], 1);
  __syncthreads();
  if (tid < N_EXP) base[tid] = atomicAdd(&cnt[tid], lcnt[tid]);
  __syncthreads();
  perm[e0 * CAP + base[e0] + s0] = t * 2;
  perm[e1 * CAP + base[e1] + s1] = t * 2 + 1;
}

// ---------------------------------------------------------------------------
// Transpose + fp32->bf16 convert: Wt[e][o][i] = (bf16) W[e][i][o]
// ---------------------------------------------------------------------------
__global__ __launch_bounds__(256)
void transpose_w(const float* __restrict__ W, __bf16* __restrict__ Wt) {
  __shared__ __bf16 tile[32][33];
  const int e  = blockIdx.z;
  const int i0 = blockIdx.y * 32;
  const int o0 = blockIdx.x * 32;
  const float* We  = W  + (size_t)e * C_DIM * C_DIM;
  __bf16*      Wte = Wt + (size_t)e * C_DIM * C_DIM;
  const int tx = threadIdx.x, ty = threadIdx.y;
#pragma unroll
  for (int j = 0; j < 32; j += 8)
    tile[ty + j][tx] = (__bf16)We[(size_t)(i0 + ty + j) * C_DIM + o0 + tx];
  __syncthreads();
#pragma unroll
  for (int j = 0; j < 32; j += 8)
    Wte[(size_t)(o0 + ty + j) * C_DIM + i0 + tx] = tile[tx][ty + j];
}

// ---------------------------------------------------------------------------
// Grouped GEMM: 128x128 tile, BK=64, 4 waves x (4x4 of 16x16x32 bf16 MFMA).
// global_load_lds staging with XOR chunk swizzle (row r stores its 8x16B
// chunks permuted by r&7) so fragment ds_read_b128s are 2-way-conflict free
// (unswizzled 128B rows would be 16-way). Epilogue: plain bf16 stores into
// the slot buffer packed inside d_out's y region: token t's 4 KiB =
// [buf0[t] (1024 bf16) | buf1[t] (1024 bf16)].
// ---------------------------------------------------------------------------
__global__ __launch_bounds__(256)
void moe_gemm(const __bf16* __restrict__ xb, const __bf16* __restrict__ Wt,
              const int* __restrict__ cnt, const int* __restrict__ perm,
              __bf16* __restrict__ buf) {
  const int e  = blockIdx.z;
  const int n0 = blockIdx.x * 128;
  const int m0 = blockIdx.y * 128;
  const int count = cnt[e];
  if (m0 >= count) return;

  const int*    permE = perm + e * CAP;
  const __bf16* We    = Wt + (size_t)e * C_DIM * C_DIM;

  __shared__ char AsB[16384];   // 128 rows x 128 B (64 bf16), chunk-swizzled
  __shared__ char BsB[16384];
  __bf16* As = (__bf16*)AsB;
  __bf16* Bs = (__bf16*)BsB;

  const int tid  = threadIdx.x;
  const int lane = tid & 63;
  const int wv   = tid >> 6;
  const int wr = wv >> 1, wc = wv & 1;
  const int mw = wr * 64, nw = wc * 64;
  const int l16 = lane & 15, quad = lane >> 4;

  // staging: wave wv covers tile rows [wv*32, wv*32+32), 4 GLD16 chunks of 8
  // rows each; lane -> (row = q*8 + lane/8, chunk = (lane&7) ^ (row&7)).
  const int rsub  = lane >> 3;          // 0..7
  const int chunk = (lane & 7) ^ rsub;  // XOR swizzle key = row&7
  int tk[4];
#pragma unroll
  for (int q = 0; q < 4; ++q) {
    const int i = m0 + wv * 32 + q * 8 + rsub;
    tk[q] = (i < count) ? (permE[i] >> 1) : 0;
  }
  const char* gB = (const char*)We + (size_t)(n0 + wv * 32 + rsub) * 2048 + chunk * 16;
  char* ldsA = AsB + wv * 4096;     // + q*1024; lane*16 appended by HW
  char* ldsB = BsB + wv * 4096;

  f32x4 acc[4][4];
  const f32x4 zero = {0.f, 0.f, 0.f, 0.f};
#pragma unroll
  for (int mi = 0; mi < 4; ++mi)
#pragma unroll
    for (int ni = 0; ni < 4; ++ni) acc[mi][ni] = zero;

  for (int kt = 0; kt < 16; ++kt) {
    const int kb = kt * 128;   // byte offset along K (64 bf16)
#pragma unroll
    for (int q = 0; q < 4; ++q)
      GLD16((const char*)xb + (size_t)tk[q] * 2048 + kb + chunk * 16,
            ldsA + q * 1024);
#pragma unroll
    for (int q = 0; q < 4; ++q)
      GLD16(gB + (size_t)q * 8 * 2048 + kb, ldsB + q * 1024);
    __syncthreads();

#pragma unroll
    for (int ks = 0; ks < 2; ++ks) {
      bf16x8 af[4], bfr[4];
#pragma unroll
      for (int mi = 0; mi < 4; ++mi) {
        const int rA = mw + mi * 16 + l16;
        af[mi] = *(const bf16x8*)(As + rA * 64 + (((ks * 4 + quad) ^ (rA & 7)) << 3));
      }
#pragma unroll
      for (int ni = 0; ni < 4; ++ni) {
        const int rB = nw + ni * 16 + l16;
        bfr[ni] = *(const bf16x8*)(Bs + rB * 64 + (((ks * 4 + quad) ^ (rB & 7)) << 3));
      }
#pragma unroll
      for (int mi = 0; mi < 4; ++mi)
#pragma unroll
        for (int ni = 0; ni < 4; ++ni)
          acc[mi][ni] = __builtin_amdgcn_mfma_f32_16x16x32_bf16(
              af[mi], bfr[ni], acc[mi][ni], 0, 0, 0);
    }
    __syncthreads();
  }

  // epilogue: C/D layout col = lane&15, row = quad*4 + reg
#pragma unroll
  for (int mi = 0; mi < 4; ++mi) {
#pragma unroll
    for (int r = 0; r < 4; ++r) {
      const int i = m0 + mw + mi * 16 + quad * 4 + r;
      if (i < count) {
        const int pe = permE[i];
        __bf16* orow = buf + (size_t)(pe >> 1) * 2048 + (pe & 1) * 1024 +
                       n0 + nw + l16;
#pragma unroll
        for (int ni = 0; ni < 4; ++ni)
          orow[ni * 16] = (__bf16)acc[mi][ni][r];
      }
    }
  }
}

// ---------------------------------------------------------------------------
// Combine, IN PLACE: block t exclusively owns y[t]'s 4 KiB, which currently
// holds [buf0[t] bf16 x1024 | buf1[t] bf16 x1024]. Load both halves, barrier
// (drains vmcnt before s_barrier), overwrite with fp32 y.
// ---------------------------------------------------------------------------
__global__ __launch_bounds__(256)
void combine(const float* __restrict__ probs, float* __restrict__ y) {
  const int t = blockIdx.x;
  const int c = threadIdx.x * 4;
  const __bf16* bt = (const __bf16*)(y + (size_t)t * C_DIM);
  const bf16x4v b0 = *(const bf16x4v*)(bt + c);
  const bf16x4v b1 = *(const bf16x4v*)(bt + 1024 + c);
  const float p0 = probs[2 * t], p1 = probs[2 * t + 1];
  __syncthreads();   // all reads of this block's region complete before writes
  float4 o = { p0 * (float)b0[0] + p1 * (float)b1[0],
               p0 * (float)b0[1] + p1 * (float)b1[1],
               p0 * (float)b0[2] + p1 * (float)b1[2],
               p0 * (float)b0[3] + p1 * (float)b1[3] };
  *(float4*)(y + (size_t)t * C_DIM + c) = o;
}

extern "C" void kernel_launch(void* const* d_in, const int* in_sizes, int n_in,
                              void* d_out, int out_size, void* d_ws, size_t ws_size,
                              hipStream_t stream) {
  const float* x    = (const float*)d_in[0];
  const float* wg   = (const float*)d_in[1];
  const float* bias = (const float*)d_in[2];
  const float* wcfc = (const float*)d_in[3];

  float* y     = (float*)d_out;
  float* probs = y + (size_t)N_TOK * C_DIM;
  __bf16* buf  = (__bf16*)d_out;         // slot buffers packed in y region

  char* ws   = (char*)d_ws;
  int*    cnt    = (int*)(ws + WS_CNT);
  int*    routeE = (int*)(ws + WS_ROUTE);
  int*    perm   = (int*)(ws + WS_PERM);
  __bf16* xb     = (__bf16*)(ws + WS_XB);
  __bf16* Wt     = (__bf16*)(ws + WS_WT);

  hipMemsetAsync(cnt, 0, N_EXP * sizeof(int), stream);

  router_kernel<<<N_TOK / 4, 256, 0, stream>>>(x, wg, bias, xb, routeE, probs);
  build_perm<<<N_TOK / 64, 64, 0, stream>>>(routeE, cnt, perm);
  transpose_w<<<dim3(32, 32, 8), dim3(32, 8), 0, stream>>>(wcfc, Wt);
  moe_gemm<<<dim3(8, 32, 8), 256, 0, stream>>>(xb, Wt, cnt, perm, buf);
  combine<<<N_TOK, 256, 0, stream>>>(probs, y);
}

// Round 5
// 139.689 us; speedup vs baseline: 1.8268x; 1.0143x over previous
//
#include <hip/hip_runtime.h>
#include <math.h>

typedef __attribute__((ext_vector_type(8))) __bf16 bf16x8;
typedef __attribute__((ext_vector_type(4))) __bf16 bf16x4v;
typedef __attribute__((ext_vector_type(4))) float f32x4;

#define N_TOK  4096
#define C_DIM  1024
#define N_EXP  8
#define CAP    4096

// workspace layout (bytes). ws_size ~= 256 MiB (poison-fill WRITE_SIZE evidence).
// NOTE round-3 postmortem: '<<' binds looser than '+' — keep all offsets fully
// parenthesized.
#define WS_CNT    0                                   // 32 B
#define WS_ROUTE  4096                                // 16 KB: e0|e1<<16 per token
#define WS_PERM   32768                               // 128 KB: per-expert slot lists
#define WS_XB     ((size_t)1 << 20)                   // 8 MB: x in bf16
#define WS_WT     (WS_XB + ((size_t)8 << 20))         // 16 MB: W^T bf16

// async global->LDS, 16B per lane. LDS dest is wave-uniform base + lane*16.
#define GLD16(g, l)                                                        \
  __builtin_amdgcn_global_load_lds(                                        \
      (const __attribute__((address_space(1))) void*)(g),                  \
      (__attribute__((address_space(3))) void*)(l), 16, 0, 0)

// ---------------------------------------------------------------------------
// prep: fused router (blocks 0..255) + W transpose/bf16 (blocks 256..8447).
// Router: 16 tokens/block (4 sequential per wave), wg staged transposed in
// LDS once per block; no atomics; zeroes cnt (block 0). Transpose: 32x32
// tiles, Wt[e][o][i] = (bf16) W[e][i][o].
// ---------------------------------------------------------------------------
__global__ __launch_bounds__(256)
void prep_kernel(const float* __restrict__ x, const float* __restrict__ wg,
                 const float* __restrict__ bias, const float* __restrict__ W,
                 __bf16* __restrict__ xb, int* __restrict__ routeE,
                 float* __restrict__ probs, __bf16* __restrict__ Wt,
                 int* __restrict__ cnt) {
  __shared__ __align__(16) char smem[32768];
  const int tid = threadIdx.x;

  if (blockIdx.x < 256) {
    // ---------------- router ----------------
    float (*wgT)[C_DIM] = (float (*)[C_DIM])smem;   // [N_EXP][C_DIM], 32 KB
    if (blockIdx.x == 0 && tid < N_EXP) cnt[tid] = 0;

#pragma unroll
    for (int i = 0; i < 8; ++i) {
      const float4 v = ((const float4*)wg)[i * 256 + tid];
      const int f = (i * 256 + tid) * 4;
      const int c = f >> 3;
      const int e = f & 7;
      wgT[e][c] = v.x; wgT[e + 1][c] = v.y; wgT[e + 2][c] = v.z; wgT[e + 3][c] = v.w;
    }
    __syncthreads();

    const int lane = tid & 63;
    const int wv   = tid >> 6;

    for (int s = 0; s < 4; ++s) {
      const int t = blockIdx.x * 16 + wv * 4 + s;
      const float4* xrow = (const float4*)(x + (size_t)t * C_DIM);
      float acc[N_EXP];
#pragma unroll
      for (int e = 0; e < N_EXP; ++e) acc[e] = 0.f;

#pragma unroll
      for (int j = 0; j < 4; ++j) {
        const int c4 = j * 64 + lane;
        const float4 v = xrow[c4];
        bf16x4v bv = { (__bf16)v.x, (__bf16)v.y, (__bf16)v.z, (__bf16)v.w };
        *(bf16x4v*)(xb + (size_t)t * C_DIM + c4 * 4) = bv;
#pragma unroll
        for (int e = 0; e < N_EXP; ++e) {
          const float4 w = *(const float4*)&wgT[e][c4 * 4];
          acc[e] += v.x * w.x + v.y * w.y + v.z * w.z + v.w * w.w;
        }
      }

#pragma unroll
      for (int off = 32; off >= 1; off >>= 1) {
#pragma unroll
        for (int e = 0; e < N_EXP; ++e) acc[e] += __shfl_xor(acc[e], off, 64);
      }

      if (lane == 0) {
        float l[N_EXP];
#pragma unroll
        for (int e = 0; e < N_EXP; ++e) l[e] = acc[e] + bias[e];
        int e0 = 0;
#pragma unroll
        for (int e = 1; e < N_EXP; ++e) if (l[e] > l[e0]) e0 = e;
        int e1 = (e0 == 0) ? 1 : 0;
#pragma unroll
        for (int e = 0; e < N_EXP; ++e) if (e != e0 && l[e] > l[e1]) e1 = e;
        const float p0 = 1.f / (1.f + expf(l[e1] - l[e0]));
        probs[t * 2]     = p0;
        probs[t * 2 + 1] = 1.f - p0;
        routeE[t] = e0 | (e1 << 16);
      }
    }
  } else {
    // ---------------- W transpose + bf16 convert ----------------
    __bf16 (*tile)[33] = (__bf16 (*)[33])smem;      // [32][33]
    const int b  = blockIdx.x - 256;
    const int e  = b >> 10;
    const int r  = b & 1023;
    const int i0 = (r >> 5) * 32;
    const int o0 = (r & 31) * 32;
    const float* We  = W  + (size_t)e * C_DIM * C_DIM;
    __bf16*      Wte = Wt + (size_t)e * C_DIM * C_DIM;
    const int tx = tid & 31, ty = tid >> 5;
#pragma unroll
    for (int j = 0; j < 32; j += 8)
      tile[ty + j][tx] = (__bf16)We[(size_t)(i0 + ty + j) * C_DIM + o0 + tx];
    __syncthreads();
#pragma unroll
    for (int j = 0; j < 32; j += 8)
      Wte[(size_t)(o0 + ty + j) * C_DIM + i0 + tx] = tile[tx][ty + j];
  }
}

// ---------------------------------------------------------------------------
// Slot assignment: 64 blocks x 64 tokens; LDS-aggregated, 8 global atomics
// per block. perm entry = token*2 + choice.
// ---------------------------------------------------------------------------
__global__ __launch_bounds__(64)
void build_perm(const int* __restrict__ routeE, int* __restrict__ cnt,
                int* __restrict__ perm) {
  __shared__ int lcnt[N_EXP], base[N_EXP];
  const int tid = threadIdx.x;
  if (tid < N_EXP) lcnt[tid] = 0;
  __syncthreads();
  const int t  = blockIdx.x * 64 + tid;
  const int re = routeE[t];
  const int e0 = re & 0xffff, e1 = re >> 16;
  const int s0 = atomicAdd(&lcnt[e0], 1);
  const int s1 = atomicAdd(&lcnt[e1], 1);
  __syncthreads();
  if (tid < N_EXP) base[tid] = atomicAdd(&cnt[tid], lcnt[tid]);
  __syncthreads();
  perm[e0 * CAP + base[e0] + s0] = t * 2;
  perm[e1 * CAP + base[e1] + s1] = t * 2 + 1;
}

// ---------------------------------------------------------------------------
// Grouped GEMM: 128x128 tile, BK=64, 4 waves x (4x4 of 16x16x32 bf16 MFMA).
// global_load_lds staging with XOR chunk swizzle (row r stores its 8x16B
// chunks permuted by r&7) -> fragment ds_read_b128s are conflict-free.
// Epilogue: plain bf16 stores into the slot buffer packed in d_out's y
// region: token t's 4 KiB = [buf0[t] (1024 bf16) | buf1[t] (1024 bf16)].
// ---------------------------------------------------------------------------
__global__ __launch_bounds__(256)
void moe_gemm(const __bf16* __restrict__ xb, const __bf16* __restrict__ Wt,
              const int* __restrict__ cnt, const int* __restrict__ perm,
              __bf16* __restrict__ buf) {
  const int e  = blockIdx.z;
  const int n0 = blockIdx.x * 128;
  const int m0 = blockIdx.y * 128;
  const int count = cnt[e];
  if (m0 >= count) return;

  const int*    permE = perm + e * CAP;
  const __bf16* We    = Wt + (size_t)e * C_DIM * C_DIM;

  __shared__ char AsB[16384];   // 128 rows x 128 B (64 bf16), chunk-swizzled
  __shared__ char BsB[16384];
  __bf16* As = (__bf16*)AsB;
  __bf16* Bs = (__bf16*)BsB;

  const int tid  = threadIdx.x;
  const int lane = tid & 63;
  const int wv   = tid >> 6;
  const int wr = wv >> 1, wc = wv & 1;
  const int mw = wr * 64, nw = wc * 64;
  const int l16 = lane & 15, quad = lane >> 4;

  const int rsub  = lane >> 3;          // 0..7
  const int chunk = (lane & 7) ^ rsub;  // XOR swizzle key = row&7
  int tk[4];
#pragma unroll
  for (int q = 0; q < 4; ++q) {
    const int i = m0 + wv * 32 + q * 8 + rsub;
    tk[q] = (i < count) ? (permE[i] >> 1) : 0;
  }
  const char* gB = (const char*)We + (size_t)(n0 + wv * 32 + rsub) * 2048 + chunk * 16;
  char* ldsA = AsB + wv * 4096;     // + q*1024; lane*16 appended by HW
  char* ldsB = BsB + wv * 4096;

  f32x4 acc[4][4];
  const f32x4 zero = {0.f, 0.f, 0.f, 0.f};
#pragma unroll
  for (int mi = 0; mi < 4; ++mi)
#pragma unroll
    for (int ni = 0; ni < 4; ++ni) acc[mi][ni] = zero;

  for (int kt = 0; kt < 16; ++kt) {
    const int kb = kt * 128;   // byte offset along K (64 bf16)
#pragma unroll
    for (int q = 0; q < 4; ++q)
      GLD16((const char*)xb + (size_t)tk[q] * 2048 + kb + chunk * 16,
            ldsA + q * 1024);
#pragma unroll
    for (int q = 0; q < 4; ++q)
      GLD16(gB + (size_t)q * 8 * 2048 + kb, ldsB + q * 1024);
    __syncthreads();

#pragma unroll
    for (int ks = 0; ks < 2; ++ks) {
      bf16x8 af[4], bfr[4];
#pragma unroll
      for (int mi = 0; mi < 4; ++mi) {
        const int rA = mw + mi * 16 + l16;
        af[mi] = *(const bf16x8*)(As + rA * 64 + (((ks * 4 + quad) ^ (rA & 7)) << 3));
      }
#pragma unroll
      for (int ni = 0; ni < 4; ++ni) {
        const int rB = nw + ni * 16 + l16;
        bfr[ni] = *(const bf16x8*)(Bs + rB * 64 + (((ks * 4 + quad) ^ (rB & 7)) << 3));
      }
#pragma unroll
      for (int mi = 0; mi < 4; ++mi)
#pragma unroll
        for (int ni = 0; ni < 4; ++ni)
          acc[mi][ni] = __builtin_amdgcn_mfma_f32_16x16x32_bf16(
              af[mi], bfr[ni], acc[mi][ni], 0, 0, 0);
    }
    __syncthreads();
  }

  // epilogue: C/D layout col = lane&15, row = quad*4 + reg
#pragma unroll
  for (int mi = 0; mi < 4; ++mi) {
#pragma unroll
    for (int r = 0; r < 4; ++r) {
      const int i = m0 + mw + mi * 16 + quad * 4 + r;
      if (i < count) {
        const int pe = permE[i];
        __bf16* orow = buf + (size_t)(pe >> 1) * 2048 + (pe & 1) * 1024 +
                       n0 + nw + l16;
#pragma unroll
        for (int ni = 0; ni < 4; ++ni)
          orow[ni * 16] = (__bf16)acc[mi][ni][r];
      }
    }
  }
}

// ---------------------------------------------------------------------------
// Combine, IN PLACE: block t exclusively owns y[t]'s 4 KiB, which currently
// holds [buf0[t] bf16 x1024 | buf1[t] bf16 x1024]. Load both halves, barrier
// (drains vmcnt before s_barrier), overwrite with fp32 y.
// ---------------------------------------------------------------------------
__global__ __launch_bounds__(256)
void combine(const float* __restrict__ probs, float* __restrict__ y) {
  const int t = blockIdx.x;
  const int c = threadIdx.x * 4;
  const __bf16* bt = (const __bf16*)(y + (size_t)t * C_DIM);
  const bf16x4v b0 = *(const bf16x4v*)(bt + c);
  const bf16x4v b1 = *(const bf16x4v*)(bt + 1024 + c);
  const float p0 = probs[2 * t], p1 = probs[2 * t + 1];
  __syncthreads();   // all reads of this block's region complete before writes
  float4 o = { p0 * (float)b0[0] + p1 * (float)b1[0],
               p0 * (float)b0[1] + p1 * (float)b1[1],
               p0 * (float)b0[2] + p1 * (float)b1[2],
               p0 * (float)b0[3] + p1 * (float)b1[3] };
  *(float4*)(y + (size_t)t * C_DIM + c) = o;
}

extern "C" void kernel_launch(void* const* d_in, const int* in_sizes, int n_in,
                              void* d_out, int out_size, void* d_ws, size_t ws_size,
                              hipStream_t stream) {
  const float* x    = (const float*)d_in[0];
  const float* wg   = (const float*)d_in[1];
  const float* bias = (const float*)d_in[2];
  const float* wcfc = (const float*)d_in[3];

  float* y     = (float*)d_out;
  float* probs = y + (size_t)N_TOK * C_DIM;
  __bf16* buf  = (__bf16*)d_out;         // slot buffers packed in y region

  char* ws   = (char*)d_ws;
  int*    cnt    = (int*)(ws + WS_CNT);
  int*    routeE = (int*)(ws + WS_ROUTE);
  int*    perm   = (int*)(ws + WS_PERM);
  __bf16* xb     = (__bf16*)(ws + WS_XB);
  __bf16* Wt     = (__bf16*)(ws + WS_WT);

  prep_kernel<<<256 + 8192, 256, 0, stream>>>(x, wg, bias, wcfc, xb, routeE,
                                              probs, Wt, cnt);
  build_perm<<<N_TOK / 64, 64, 0, stream>>>(routeE, cnt, perm);
  moe_gemm<<<dim3(8, 32, 8), 256, 0, stream>>>(xb, Wt, cnt, perm, buf);
  combine<<<N_TOK, 256, 0, stream>>>(probs, y);
}